// Round 1
// baseline (1149.139 us; speedup 1.0000x reference)
//
#include <hip/hip_runtime.h>
#include <hip/hip_bf16.h>

#define DHC 128
#define SCHUNK 1024

// ---------------- graph prep ----------------

__global__ void hist_k(const int* __restrict__ dst, int* __restrict__ deg, int e) {
    int i = blockIdx.x * 256 + threadIdx.x;
    if (i < e) atomicAdd(&deg[dst[i]], 1);
}

__global__ void dinv_k(const int* __restrict__ deg, float* __restrict__ dinv,
                       float* __restrict__ selfc, int n) {
    int i = blockIdx.x * 256 + threadIdx.x;
    if (i >= n) return;
    float dv = rsqrtf((float)(deg[i] + 1));
    dinv[i] = dv;
    selfc[i] = dv * dv;
}

__global__ void scan_partial(const int* __restrict__ deg, int* __restrict__ bsum, int n) {
    __shared__ int red[256];
    int b = blockIdx.x, t = threadIdx.x;
    int base = b * SCHUNK + t * 4;
    int s = 0;
#pragma unroll
    for (int i = 0; i < 4; i++) {
        int idx = base + i;
        if (idx < n) s += deg[idx];
    }
    red[t] = s;
    __syncthreads();
    for (int off = 128; off > 0; off >>= 1) {
        if (t < off) red[t] += red[t + off];
        __syncthreads();
    }
    if (t == 0) bsum[b] = red[0];
}

__global__ void scan_bsum(int* __restrict__ bsum, int* __restrict__ row_ptr, int nblk, int n) {
    __shared__ int s[256];
    int t = threadIdx.x;
    s[t] = (t < nblk) ? bsum[t] : 0;
    __syncthreads();
    for (int off = 1; off < 256; off <<= 1) {
        int add = (t >= off) ? s[t - off] : 0;
        __syncthreads();
        s[t] += add;
        __syncthreads();
    }
    if (t < nblk) bsum[t] = (t == 0) ? 0 : s[t - 1];
    if (t == 0) row_ptr[n] = s[255];
}

__global__ void scan_final(const int* __restrict__ deg, const int* __restrict__ bsum,
                           int* __restrict__ row_ptr, int* __restrict__ cursor, int n) {
    __shared__ int red[256];
    int b = blockIdx.x, t = threadIdx.x;
    int base = b * SCHUNK + t * 4;
    int v0 = 0, v1 = 0, v2 = 0, v3 = 0;
    if (base + 0 < n) v0 = deg[base + 0];
    if (base + 1 < n) v1 = deg[base + 1];
    if (base + 2 < n) v2 = deg[base + 2];
    if (base + 3 < n) v3 = deg[base + 3];
    int tot = v0 + v1 + v2 + v3;
    red[t] = tot;
    __syncthreads();
    for (int off = 1; off < 256; off <<= 1) {
        int add = (t >= off) ? red[t - off] : 0;
        __syncthreads();
        red[t] += add;
        __syncthreads();
    }
    int ex = (t == 0) ? 0 : red[t - 1];
    int off0 = bsum[b] + ex;
    int p0 = off0;
    int p1 = off0 + v0;
    int p2 = p1 + v1;
    int p3 = p2 + v2;
    if (base + 0 < n) { row_ptr[base + 0] = p0; cursor[base + 0] = p0; }
    if (base + 1 < n) { row_ptr[base + 1] = p1; cursor[base + 1] = p1; }
    if (base + 2 < n) { row_ptr[base + 2] = p2; cursor[base + 2] = p2; }
    if (base + 3 < n) { row_ptr[base + 3] = p3; cursor[base + 3] = p3; }
}

__global__ void scatter_k(const int* __restrict__ src, const int* __restrict__ dst,
                          const float* __restrict__ dinv, int* __restrict__ cursor,
                          int2* __restrict__ packed, int e) {
    int i = blockIdx.x * 256 + threadIdx.x;
    if (i >= e) return;
    int s = src[i], d = dst[i];
    float c = dinv[s] * dinv[d];
    int pos = atomicAdd(&cursor[d], 1);
    packed[pos] = make_int2(s, __float_as_int(c));
}

// ---------------- dense GEMM: out[N,128] = A[N,128] @ W[128,128] ----------------
// MODE 0: plain store.  MODE 1: relu(acc + bias) store.
template <int MODE>
__global__ __launch_bounds__(256) void gemm_k(const float* __restrict__ A,
                                              const float* __restrict__ W,
                                              const float* __restrict__ bias,
                                              float* __restrict__ out, int n) {
    __shared__ float4 Ws4[4096];  // 64 KB, W row-major as float4
    {
        const float4* W4 = (const float4*)W;
        for (int i = threadIdx.x; i < 4096; i += 256) Ws4[i] = W4[i];
    }
    __syncthreads();
    const int rg = threadIdx.x >> 3;  // 0..31 -> 8 rows each
    const int cg = threadIdx.x & 7;   // 0..7  -> 16 cols each
    const int r0 = blockIdx.x * 256 + rg * 8;
    const int c4 = cg * 4;  // float4 column index
    const float4* A4 = (const float4*)A;
    size_t rowIdx[8];
#pragma unroll
    for (int i = 0; i < 8; i++) {
        int r = r0 + i;
        rowIdx[i] = (size_t)((r < n) ? r : 0) * 32;
    }
    float4 acc[8][4];
#pragma unroll
    for (int i = 0; i < 8; i++)
#pragma unroll
        for (int j = 0; j < 4; j++) acc[i][j] = make_float4(0.f, 0.f, 0.f, 0.f);

    for (int k4 = 0; k4 < 32; k4++) {
        float4 xv[8];
#pragma unroll
        for (int i = 0; i < 8; i++) xv[i] = A4[rowIdx[i] + k4];
#pragma unroll
        for (int kk = 0; kk < 4; kk++) {
            const float4 w0 = Ws4[(k4 * 4 + kk) * 32 + c4 + 0];
            const float4 w1 = Ws4[(k4 * 4 + kk) * 32 + c4 + 1];
            const float4 w2 = Ws4[(k4 * 4 + kk) * 32 + c4 + 2];
            const float4 w3 = Ws4[(k4 * 4 + kk) * 32 + c4 + 3];
#pragma unroll
            for (int i = 0; i < 8; i++) {
                float xs = (kk == 0) ? xv[i].x : (kk == 1) ? xv[i].y : (kk == 2) ? xv[i].z : xv[i].w;
                acc[i][0].x = fmaf(xs, w0.x, acc[i][0].x);
                acc[i][0].y = fmaf(xs, w0.y, acc[i][0].y);
                acc[i][0].z = fmaf(xs, w0.z, acc[i][0].z);
                acc[i][0].w = fmaf(xs, w0.w, acc[i][0].w);
                acc[i][1].x = fmaf(xs, w1.x, acc[i][1].x);
                acc[i][1].y = fmaf(xs, w1.y, acc[i][1].y);
                acc[i][1].z = fmaf(xs, w1.z, acc[i][1].z);
                acc[i][1].w = fmaf(xs, w1.w, acc[i][1].w);
                acc[i][2].x = fmaf(xs, w2.x, acc[i][2].x);
                acc[i][2].y = fmaf(xs, w2.y, acc[i][2].y);
                acc[i][2].z = fmaf(xs, w2.z, acc[i][2].z);
                acc[i][2].w = fmaf(xs, w2.w, acc[i][2].w);
                acc[i][3].x = fmaf(xs, w3.x, acc[i][3].x);
                acc[i][3].y = fmaf(xs, w3.y, acc[i][3].y);
                acc[i][3].z = fmaf(xs, w3.z, acc[i][3].z);
                acc[i][3].w = fmaf(xs, w3.w, acc[i][3].w);
            }
        }
    }

    float4 bv[4];
    if (MODE == 1) {
        const float4* b4 = (const float4*)bias;
#pragma unroll
        for (int j = 0; j < 4; j++) bv[j] = b4[c4 + j];
    }
#pragma unroll
    for (int i = 0; i < 8; i++) {
        int r = r0 + i;
        if (r < n) {
            float4* o4 = (float4*)(out + (size_t)r * DHC) + c4;
#pragma unroll
            for (int j = 0; j < 4; j++) {
                float4 v = acc[i][j];
                if (MODE == 1) {
                    v.x = fmaxf(v.x + bv[j].x, 0.f);
                    v.y = fmaxf(v.y + bv[j].y, 0.f);
                    v.z = fmaxf(v.z + bv[j].z, 0.f);
                    v.w = fmaxf(v.w + bv[j].w, 0.f);
                }
                o4[j] = v;
            }
        }
    }
}

// ---------------- CSR gather aggregation + self-loop + bias + relu ----------------
// One wave (64 lanes) per dst node; each lane owns 2 channels (float2).
__global__ __launch_bounds__(256) void agg_k(const float* __restrict__ hW,
                                             const int2* __restrict__ packed,
                                             const int* __restrict__ row_ptr,
                                             const float* __restrict__ selfc,
                                             const float* __restrict__ bias,
                                             float* __restrict__ out, int n) {
    int node = blockIdx.x * 4 + (threadIdx.x >> 6);
    int lane = threadIdx.x & 63;
    if (node >= n) return;
    int beg = row_ptr[node], end = row_ptr[node + 1];
    const float2* hw2 = (const float2*)hW;
    float ax = 0.f, ay = 0.f;
    for (int e = beg; e < end; e++) {
        int2 p = packed[e];
        float c = __int_as_float(p.y);
        float2 v = hw2[(size_t)p.x * 64 + lane];
        ax = fmaf(c, v.x, ax);
        ay = fmaf(c, v.y, ay);
    }
    float sc = selfc[node];
    float2 hv = hw2[(size_t)node * 64 + lane];
    float2 bv = ((const float2*)bias)[lane];
    float ox = fmaxf(fmaf(sc, hv.x, ax) + bv.x, 0.f);
    float oy = fmaxf(fmaf(sc, hv.y, ay) + bv.y, 0.f);
    float2* o2 = (float2*)out;
    o2[(size_t)node * 64 + lane] = make_float2(ox, oy);
}

// ---------------- BN stats (per-channel sum / sumsq) ----------------
__global__ __launch_bounds__(256) void bn_stats(const float* __restrict__ h,
                                                float* __restrict__ gsum,
                                                float* __restrict__ gsumsq, int n) {
    __shared__ float s1[256], s2[256];
    int c = threadIdx.x & 127;
    int half = threadIdx.x >> 7;
    float sum = 0.f, sumsq = 0.f;
    for (int r = blockIdx.x * 2 + half; r < n; r += gridDim.x * 2) {
        float v = h[(size_t)r * DHC + c];
        sum += v;
        sumsq = fmaf(v, v, sumsq);
    }
    s1[threadIdx.x] = sum;
    s2[threadIdx.x] = sumsq;
    __syncthreads();
    if (threadIdx.x < 128) {
        atomicAdd(&gsum[c], s1[threadIdx.x] + s1[threadIdx.x + 128]);
        atomicAdd(&gsumsq[c], s2[threadIdx.x] + s2[threadIdx.x + 128]);
    }
}

// ---------------- fold BN into Wc: Wc' = diag(scale)Wc, bc' = shift@Wc + bc ----------------
__global__ void bn_fold(const float* __restrict__ gsum, const float* __restrict__ gsumsq,
                        const float* __restrict__ gamma, const float* __restrict__ beta,
                        const float* __restrict__ Wc, const float* __restrict__ bc,
                        float* __restrict__ WcP, float* __restrict__ bcP, float invN) {
    __shared__ float scaleS[128], shiftS[128];
    int j = threadIdx.x;
    float mu = gsum[j] * invN;
    float var = gsumsq[j] * invN - mu * mu;
    float sc = gamma[j] * rsqrtf(var + 1e-5f);
    scaleS[j] = sc;
    shiftS[j] = beta[j] - mu * sc;
    __syncthreads();
    float accB = bc[j];
    for (int k = 0; k < 128; k++) {
        float w = Wc[k * 128 + j];
        WcP[k * 128 + j] = scaleS[k] * w;
        accB = fmaf(shiftS[k], w, accB);
    }
    bcP[j] = accB;
}

// ---------------- final projection: out[N,2] = T[N,128] @ Wr + br ----------------
__global__ __launch_bounds__(256) void out_proj(const float* __restrict__ T,
                                                const float* __restrict__ Wr,
                                                const float* __restrict__ br,
                                                float* __restrict__ out, int n) {
    __shared__ float2 WrS[128];
    if (threadIdx.x < 128) {
        WrS[threadIdx.x] = make_float2(Wr[threadIdx.x * 2], Wr[threadIdx.x * 2 + 1]);
    }
    __syncthreads();
    int r = blockIdx.x * 256 + threadIdx.x;
    if (r >= n) return;
    const float4* t4 = (const float4*)(T + (size_t)r * DHC);
    float a0 = 0.f, a1 = 0.f;
#pragma unroll
    for (int j4 = 0; j4 < 32; j4++) {
        float4 v = t4[j4];
        float2 w0 = WrS[j4 * 4 + 0];
        float2 w1 = WrS[j4 * 4 + 1];
        float2 w2 = WrS[j4 * 4 + 2];
        float2 w3 = WrS[j4 * 4 + 3];
        a0 += v.x * w0.x + v.y * w1.x + v.z * w2.x + v.w * w3.x;
        a1 += v.x * w0.y + v.y * w1.y + v.z * w2.y + v.w * w3.y;
    }
    ((float2*)out)[r] = make_float2(a0 + br[0], a1 + br[1]);
}

// ---------------- host ----------------

extern "C" void kernel_launch(void* const* d_in, const int* in_sizes, int n_in,
                              void* d_out, int out_size, void* d_ws, size_t ws_size,
                              hipStream_t stream) {
    const float* x = (const float*)d_in[0];
    const int* ei = (const int*)d_in[1];
    const float* W1 = (const float*)d_in[2];
    const float* b1 = (const float*)d_in[3];
    const float* W2 = (const float*)d_in[4];
    const float* b2 = (const float*)d_in[5];
    const float* W3 = (const float*)d_in[6];
    const float* b3 = (const float*)d_in[7];
    const float* gamma = (const float*)d_in[8];
    const float* beta = (const float*)d_in[9];
    const float* Wc = (const float*)d_in[10];
    const float* bc = (const float*)d_in[11];
    const float* Wr = (const float*)d_in[12];
    const float* br = (const float*)d_in[13];
    float* out = (float*)d_out;

    const int N = in_sizes[0] / DHC;
    const int E = in_sizes[1] / 2;
    const int* srcIdx = ei;
    const int* dstIdx = ei + E;

    // workspace carve-up
    char* w = (char*)d_ws;
    size_t off = 0;
    auto alloc = [&](size_t bytes) -> void* {
        void* p = w + off;
        off += (bytes + 255) & ~(size_t)255;
        return p;
    };
    float* bufA = (float*)alloc((size_t)N * DHC * 4);
    float* bufB = (float*)alloc((size_t)N * DHC * 4);
    int2* packed = (int2*)alloc((size_t)E * 8);
    int* deg = (int*)alloc((size_t)N * 4);
    int* row_ptr = (int*)alloc((size_t)(N + 1) * 4);
    int* cursor = (int*)alloc((size_t)N * 4);
    float* dinv = (float*)alloc((size_t)N * 4);
    float* selfc = (float*)alloc((size_t)N * 4);
    int* bsum = (int*)alloc(256 * 4);
    float* stats = (float*)alloc(256 * 4);  // gsum[128] ++ gsumsq[128]
    float* gsum = stats;
    float* gsumsq = stats + 128;
    float* WcP = (float*)alloc(128 * 128 * 4);
    float* bcP = (float*)alloc(128 * 4);
    (void)ws_size; (void)n_in; (void)out_size;

    const int NBLK = (N + SCHUNK - 1) / SCHUNK;

    hipMemsetAsync(deg, 0, (size_t)N * 4, stream);
    hipMemsetAsync(stats, 0, 256 * 4, stream);

    // graph prep
    hist_k<<<(E + 255) / 256, 256, 0, stream>>>(dstIdx, deg, E);
    dinv_k<<<(N + 255) / 256, 256, 0, stream>>>(deg, dinv, selfc, N);
    scan_partial<<<NBLK, 256, 0, stream>>>(deg, bsum, N);
    scan_bsum<<<1, 256, 0, stream>>>(bsum, row_ptr, NBLK, N);
    scan_final<<<NBLK, 256, 0, stream>>>(deg, bsum, row_ptr, cursor, N);
    scatter_k<<<(E + 255) / 256, 256, 0, stream>>>(srcIdx, dstIdx, dinv, cursor, packed, E);

    const int gemmBlocks = (N + 255) / 256;
    const int aggBlocks = (N + 3) / 4;

    // layer 1
    gemm_k<0><<<gemmBlocks, 256, 0, stream>>>(x, W1, nullptr, bufB, N);
    agg_k<<<aggBlocks, 256, 0, stream>>>(bufB, packed, row_ptr, selfc, b1, bufA, N);
    // layer 2
    gemm_k<0><<<gemmBlocks, 256, 0, stream>>>(bufA, W2, nullptr, bufB, N);
    agg_k<<<aggBlocks, 256, 0, stream>>>(bufB, packed, row_ptr, selfc, b2, bufA, N);
    // layer 3
    gemm_k<0><<<gemmBlocks, 256, 0, stream>>>(bufA, W3, nullptr, bufB, N);
    agg_k<<<aggBlocks, 256, 0, stream>>>(bufB, packed, row_ptr, selfc, b3, bufA, N);

    // batchnorm (training-mode batch stats), folded into classifier GEMM
    bn_stats<<<256, 256, 0, stream>>>(bufA, gsum, gsumsq, N);
    bn_fold<<<1, 128, 0, stream>>>(gsum, gsumsq, gamma, beta, Wc, bc, WcP, bcP, 1.0f / (float)N);

    // classifier: relu(h @ Wc' + bc') @ Wr + br
    gemm_k<1><<<gemmBlocks, 256, 0, stream>>>(bufA, WcP, bcP, bufB, N);
    out_proj<<<gemmBlocks, 256, 0, stream>>>(bufB, Wr, br, out, N);
}

// Round 2
// 636.904 us; speedup vs baseline: 1.8043x; 1.8043x over previous
//
#include <hip/hip_runtime.h>

#define DHC 128
#define SCHUNK 1024

typedef __attribute__((ext_vector_type(8))) __bf16 bf16x8;
typedef __attribute__((ext_vector_type(8))) unsigned short ushort8;
typedef __attribute__((ext_vector_type(4))) float floatx4;

__device__ inline unsigned short f2bf(float f) {
    unsigned int u = __float_as_uint(f);
    return (unsigned short)((u + 0x7FFFu + ((u >> 16) & 1u)) >> 16);
}
__device__ inline float bf2f_lo(unsigned int v) { return __uint_as_float(v << 16); }
__device__ inline float bf2f_hi(unsigned int v) { return __uint_as_float(v & 0xFFFF0000u); }

// ---------------- graph prep ----------------

__global__ void hist_k(const int* __restrict__ dst, int* __restrict__ deg, int e) {
    int i = blockIdx.x * 256 + threadIdx.x;
    if (i < e) atomicAdd(&deg[dst[i]], 1);
}

__global__ void dinv_k(const int* __restrict__ deg, float* __restrict__ dinv,
                       float* __restrict__ selfc, int n) {
    int i = blockIdx.x * 256 + threadIdx.x;
    if (i >= n) return;
    float dv = rsqrtf((float)(deg[i] + 1));
    dinv[i] = dv;
    selfc[i] = dv * dv;
}

__global__ void scan_partial(const int* __restrict__ deg, int* __restrict__ bsum, int n) {
    __shared__ int red[256];
    int b = blockIdx.x, t = threadIdx.x;
    int base = b * SCHUNK + t * 4;
    int s = 0;
#pragma unroll
    for (int i = 0; i < 4; i++) {
        int idx = base + i;
        if (idx < n) s += deg[idx];
    }
    red[t] = s;
    __syncthreads();
    for (int off = 128; off > 0; off >>= 1) {
        if (t < off) red[t] += red[t + off];
        __syncthreads();
    }
    if (t == 0) bsum[b] = red[0];
}

__global__ void scan_bsum(int* __restrict__ bsum, int* __restrict__ row_ptr, int nblk, int n) {
    __shared__ int s[256];
    int t = threadIdx.x;
    s[t] = (t < nblk) ? bsum[t] : 0;
    __syncthreads();
    for (int off = 1; off < 256; off <<= 1) {
        int add = (t >= off) ? s[t - off] : 0;
        __syncthreads();
        s[t] += add;
        __syncthreads();
    }
    if (t < nblk) bsum[t] = (t == 0) ? 0 : s[t - 1];
    if (t == 0) row_ptr[n] = s[255];
}

__global__ void scan_final(const int* __restrict__ deg, const int* __restrict__ bsum,
                           int* __restrict__ row_ptr, int* __restrict__ cursor, int n) {
    __shared__ int red[256];
    int b = blockIdx.x, t = threadIdx.x;
    int base = b * SCHUNK + t * 4;
    int v0 = 0, v1 = 0, v2 = 0, v3 = 0;
    if (base + 0 < n) v0 = deg[base + 0];
    if (base + 1 < n) v1 = deg[base + 1];
    if (base + 2 < n) v2 = deg[base + 2];
    if (base + 3 < n) v3 = deg[base + 3];
    int tot = v0 + v1 + v2 + v3;
    red[t] = tot;
    __syncthreads();
    for (int off = 1; off < 256; off <<= 1) {
        int add = (t >= off) ? red[t - off] : 0;
        __syncthreads();
        red[t] += add;
        __syncthreads();
    }
    int ex = (t == 0) ? 0 : red[t - 1];
    int off0 = bsum[b] + ex;
    int p0 = off0;
    int p1 = off0 + v0;
    int p2 = p1 + v1;
    int p3 = p2 + v2;
    if (base + 0 < n) { row_ptr[base + 0] = p0; cursor[base + 0] = p0; }
    if (base + 1 < n) { row_ptr[base + 1] = p1; cursor[base + 1] = p1; }
    if (base + 2 < n) { row_ptr[base + 2] = p2; cursor[base + 2] = p2; }
    if (base + 3 < n) { row_ptr[base + 3] = p3; cursor[base + 3] = p3; }
}

__global__ void scatter_k(const int* __restrict__ src, const int* __restrict__ dst,
                          const float* __restrict__ dinv, int* __restrict__ cursor,
                          int2* __restrict__ packed, int e) {
    int i = blockIdx.x * 256 + threadIdx.x;
    if (i >= e) return;
    int s = src[i], d = dst[i];
    float c = dinv[s] * dinv[d];
    int pos = atomicAdd(&cursor[d], 1);
    packed[pos] = make_int2(s, __float_as_int(c));
}

// ---------------- weight convert: W[128k][128n] fp32 -> WT[n][k] bf16 ----------------
__global__ void wconv_k(const float* __restrict__ W, unsigned short* __restrict__ WT) {
    int i = blockIdx.x * 256 + threadIdx.x;  // 16384
    int nn = i >> 7, k = i & 127;
    WT[i] = f2bf(W[k * 128 + nn]);
}

// ---------------- MFMA bf16 GEMM: out[N,128](bf16) = A[N,128] @ W ----------------
// WT is W^T [n][k] bf16. Block = 256 thr (4 waves), 128 rows/block.
// Wave: 2 row-tiles (32 rows) x 8 col-tiles, 16x16x32 MFMA, K=128 in 4 steps.
// MODE 0: plain bf16 store. MODE 1: relu(acc + bias) bf16 store.
// AF32: A is fp32 (convert in-flight), else bf16.
template <int MODE, int AF32>
__global__ __launch_bounds__(256) void gemm_k(const void* __restrict__ Avoid,
                                              const unsigned short* __restrict__ WT,
                                              const float* __restrict__ bias,
                                              unsigned short* __restrict__ out, int n) {
    // frag-major staging: region f = ks*8+ct holds 64 lanes x 8 ushort, lane-contiguous
    __shared__ unsigned short Ws[32 * 512];
    {
        for (int c = threadIdx.x; c < 2048; c += 256) {
            int f = c >> 6;
            int l = c & 63;
            int ks = f >> 3, ct = f & 7;
            int nn = ct * 16 + (l & 15);
            int kb = ks * 32 + (l >> 4) * 8;
            *(uint4*)(&Ws[c * 8]) = *(const uint4*)(&WT[nn * 128 + kb]);
        }
    }
    __syncthreads();
    const int wave = threadIdx.x >> 6;
    const int lane = threadIdx.x & 63;
    const int rowbase = blockIdx.x * 128 + wave * 32;
    const int m = lane & 15;
    const int kq = lane >> 4;  // 0..3

    floatx4 acc[2][8];
#pragma unroll
    for (int rt = 0; rt < 2; rt++)
#pragma unroll
        for (int ct = 0; ct < 8; ct++) acc[rt][ct] = (floatx4){0.f, 0.f, 0.f, 0.f};

    const int r0 = min(rowbase + m, n - 1);
    const int r1 = min(rowbase + 16 + m, n - 1);

#pragma unroll
    for (int ks = 0; ks < 4; ks++) {
        const int kb = ks * 32 + kq * 8;
        bf16x8 a0, a1;
        if (AF32) {
            const float* Af = (const float*)Avoid;
            float4 f00 = *(const float4*)(Af + (size_t)r0 * 128 + kb);
            float4 f01 = *(const float4*)(Af + (size_t)r0 * 128 + kb + 4);
            float4 f10 = *(const float4*)(Af + (size_t)r1 * 128 + kb);
            float4 f11 = *(const float4*)(Af + (size_t)r1 * 128 + kb + 4);
            ushort8 u0, u1;
            u0[0] = f2bf(f00.x); u0[1] = f2bf(f00.y); u0[2] = f2bf(f00.z); u0[3] = f2bf(f00.w);
            u0[4] = f2bf(f01.x); u0[5] = f2bf(f01.y); u0[6] = f2bf(f01.z); u0[7] = f2bf(f01.w);
            u1[0] = f2bf(f10.x); u1[1] = f2bf(f10.y); u1[2] = f2bf(f10.z); u1[3] = f2bf(f10.w);
            u1[4] = f2bf(f11.x); u1[5] = f2bf(f11.y); u1[6] = f2bf(f11.z); u1[7] = f2bf(f11.w);
            a0 = __builtin_bit_cast(bf16x8, u0);
            a1 = __builtin_bit_cast(bf16x8, u1);
        } else {
            const unsigned short* Ab = (const unsigned short*)Avoid;
            a0 = __builtin_bit_cast(bf16x8, *(const ushort8*)(Ab + (size_t)r0 * 128 + kb));
            a1 = __builtin_bit_cast(bf16x8, *(const ushort8*)(Ab + (size_t)r1 * 128 + kb));
        }
#pragma unroll
        for (int ct = 0; ct < 8; ct++) {
            bf16x8 b = __builtin_bit_cast(bf16x8,
                *(const ushort8*)(&Ws[(ks * 8 + ct) * 512 + lane * 8]));
            acc[0][ct] = __builtin_amdgcn_mfma_f32_16x16x32_bf16(a0, b, acc[0][ct], 0, 0, 0);
            acc[1][ct] = __builtin_amdgcn_mfma_f32_16x16x32_bf16(a1, b, acc[1][ct], 0, 0, 0);
        }
    }

#pragma unroll
    for (int rt = 0; rt < 2; rt++) {
#pragma unroll
        for (int ct = 0; ct < 8; ct++) {
            int col = ct * 16 + m;
            float bv = (MODE == 1) ? bias[col] : 0.f;
#pragma unroll
            for (int i = 0; i < 4; i++) {
                int r = rowbase + rt * 16 + kq * 4 + i;
                if (r < n) {
                    float v = acc[rt][ct][i];
                    if (MODE == 1) v = fmaxf(v + bv, 0.f);
                    out[(size_t)r * 128 + col] = f2bf(v);
                }
            }
        }
    }
}

// ---------------- CSR gather aggregation (bf16 payload) + self + bias + relu ----------------
// One wave per dst node; lane owns 2 channels (uint = bf16x2). 4-edge unroll for MLP.
__global__ __launch_bounds__(256) void agg_k(const unsigned short* __restrict__ hW,
                                             const int2* __restrict__ packed,
                                             const int* __restrict__ row_ptr,
                                             const float* __restrict__ selfc,
                                             const float* __restrict__ bias,
                                             unsigned short* __restrict__ out, int n) {
    int node = blockIdx.x * 4 + (threadIdx.x >> 6);
    int lane = threadIdx.x & 63;
    if (node >= n) return;
    int e = row_ptr[node], end = row_ptr[node + 1];
    const unsigned int* hw1 = (const unsigned int*)hW;
    float ax = 0.f, ay = 0.f;
    for (; e + 4 <= end; e += 4) {
        int2 p0 = packed[e + 0];
        int2 p1 = packed[e + 1];
        int2 p2 = packed[e + 2];
        int2 p3 = packed[e + 3];
        unsigned int v0 = hw1[(size_t)p0.x * 64 + lane];
        unsigned int v1 = hw1[(size_t)p1.x * 64 + lane];
        unsigned int v2 = hw1[(size_t)p2.x * 64 + lane];
        unsigned int v3 = hw1[(size_t)p3.x * 64 + lane];
        float c0 = __int_as_float(p0.y);
        float c1 = __int_as_float(p1.y);
        float c2 = __int_as_float(p2.y);
        float c3 = __int_as_float(p3.y);
        ax = fmaf(c0, bf2f_lo(v0), ax); ay = fmaf(c0, bf2f_hi(v0), ay);
        ax = fmaf(c1, bf2f_lo(v1), ax); ay = fmaf(c1, bf2f_hi(v1), ay);
        ax = fmaf(c2, bf2f_lo(v2), ax); ay = fmaf(c2, bf2f_hi(v2), ay);
        ax = fmaf(c3, bf2f_lo(v3), ax); ay = fmaf(c3, bf2f_hi(v3), ay);
    }
    for (; e < end; e++) {
        int2 p = packed[e];
        unsigned int v = hw1[(size_t)p.x * 64 + lane];
        float c = __int_as_float(p.y);
        ax = fmaf(c, bf2f_lo(v), ax);
        ay = fmaf(c, bf2f_hi(v), ay);
    }
    float sc = selfc[node];
    unsigned int hv = hw1[(size_t)node * 64 + lane];
    float2 bv = ((const float2*)bias)[lane];
    float ox = fmaxf(fmaf(sc, bf2f_lo(hv), ax) + bv.x, 0.f);
    float oy = fmaxf(fmaf(sc, bf2f_hi(hv), ay) + bv.y, 0.f);
    unsigned int o = (unsigned int)f2bf(ox) | ((unsigned int)f2bf(oy) << 16);
    ((unsigned int*)out)[(size_t)node * 64 + lane] = o;
}

// ---------------- BN stats (per-channel sum / sumsq) over bf16 h ----------------
__global__ __launch_bounds__(256) void bn_stats(const unsigned short* __restrict__ h,
                                                float* __restrict__ gsum,
                                                float* __restrict__ gsumsq, int n) {
    __shared__ float red[4][256];
    int l = threadIdx.x & 63;   // channel pair
    int rs = threadIdx.x >> 6;  // row stream 0..3
    float s0 = 0.f, s1 = 0.f, q0 = 0.f, q1 = 0.f;
    for (int r = blockIdx.x * 4 + rs; r < n; r += gridDim.x * 4) {
        unsigned int v = *(const unsigned int*)(h + (size_t)r * 128 + l * 2);
        float a = bf2f_lo(v), b = bf2f_hi(v);
        s0 += a; s1 += b;
        q0 = fmaf(a, a, q0);
        q1 = fmaf(b, b, q1);
    }
    red[0][threadIdx.x] = s0;
    red[1][threadIdx.x] = s1;
    red[2][threadIdx.x] = q0;
    red[3][threadIdx.x] = q1;
    __syncthreads();
    if (threadIdx.x < 64) {
        float S0 = 0.f, S1 = 0.f, Q0 = 0.f, Q1 = 0.f;
#pragma unroll
        for (int j = 0; j < 4; j++) {
            S0 += red[0][j * 64 + l];
            S1 += red[1][j * 64 + l];
            Q0 += red[2][j * 64 + l];
            Q1 += red[3][j * 64 + l];
        }
        atomicAdd(&gsum[2 * l + 0], S0);
        atomicAdd(&gsum[2 * l + 1], S1);
        atomicAdd(&gsumsq[2 * l + 0], Q0);
        atomicAdd(&gsumsq[2 * l + 1], Q1);
    }
}

// ---------------- fold BN into Wc: WcT[n][k] = bf16(scale_k*Wc[k][n]); bcP fp32 ----------------
__global__ void bn_fold(const float* __restrict__ gsum, const float* __restrict__ gsumsq,
                        const float* __restrict__ gamma, const float* __restrict__ beta,
                        const float* __restrict__ Wc, const float* __restrict__ bc,
                        unsigned short* __restrict__ WcT, float* __restrict__ bcP, float invN) {
    __shared__ float scaleS[128], shiftS[128];
    int j = threadIdx.x;
    float mu = gsum[j] * invN;
    float var = gsumsq[j] * invN - mu * mu;
    float sc = gamma[j] * rsqrtf(var + 1e-5f);
    scaleS[j] = sc;
    shiftS[j] = beta[j] - mu * sc;
    __syncthreads();
    float accB = bc[j];
    for (int k = 0; k < 128; k++) {
        float w = Wc[k * 128 + j];
        WcT[j * 128 + k] = f2bf(scaleS[k] * w);
        accB = fmaf(shiftS[k], w, accB);
    }
    bcP[j] = accB;
}

// ---------------- final projection: out[N,2] fp32 = T[N,128] bf16 @ Wr + br ----------------
__global__ __launch_bounds__(256) void out_proj(const unsigned short* __restrict__ T,
                                                const float* __restrict__ Wr,
                                                const float* __restrict__ br,
                                                float* __restrict__ out, int n) {
    __shared__ float2 WrS[128];
    if (threadIdx.x < 128)
        WrS[threadIdx.x] = make_float2(Wr[threadIdx.x * 2], Wr[threadIdx.x * 2 + 1]);
    __syncthreads();
    int r = blockIdx.x * 256 + threadIdx.x;
    if (r >= n) return;
    const ushort8* t8 = (const ushort8*)(T + (size_t)r * 128);
    float a0 = 0.f, a1 = 0.f;
#pragma unroll
    for (int j = 0; j < 16; j++) {
        ushort8 v = t8[j];
#pragma unroll
        for (int i = 0; i < 8; i++) {
            float x = __uint_as_float((unsigned int)v[i] << 16);
            float2 w = WrS[j * 8 + i];
            a0 = fmaf(x, w.x, a0);
            a1 = fmaf(x, w.y, a1);
        }
    }
    ((float2*)out)[r] = make_float2(a0 + br[0], a1 + br[1]);
}

// ---------------- host ----------------

extern "C" void kernel_launch(void* const* d_in, const int* in_sizes, int n_in,
                              void* d_out, int out_size, void* d_ws, size_t ws_size,
                              hipStream_t stream) {
    const float* x = (const float*)d_in[0];
    const int* ei = (const int*)d_in[1];
    const float* W1 = (const float*)d_in[2];
    const float* b1 = (const float*)d_in[3];
    const float* W2 = (const float*)d_in[4];
    const float* b2 = (const float*)d_in[5];
    const float* W3 = (const float*)d_in[6];
    const float* b3 = (const float*)d_in[7];
    const float* gamma = (const float*)d_in[8];
    const float* beta = (const float*)d_in[9];
    const float* Wc = (const float*)d_in[10];
    const float* bc = (const float*)d_in[11];
    const float* Wr = (const float*)d_in[12];
    const float* br = (const float*)d_in[13];
    float* out = (float*)d_out;

    const int N = in_sizes[0] / DHC;
    const int E = in_sizes[1] / 2;
    const int* srcIdx = ei;
    const int* dstIdx = ei + E;

    char* w = (char*)d_ws;
    size_t off = 0;
    auto alloc = [&](size_t bytes) -> void* {
        void* p = w + off;
        off += (bytes + 255) & ~(size_t)255;
        return p;
    };
    unsigned short* bufA = (unsigned short*)alloc((size_t)N * DHC * 2);
    unsigned short* bufB = (unsigned short*)alloc((size_t)N * DHC * 2);
    int2* packed = (int2*)alloc((size_t)E * 8);
    int* deg = (int*)alloc((size_t)N * 4);
    int* row_ptr = (int*)alloc((size_t)(N + 1) * 4);
    int* cursor = (int*)alloc((size_t)N * 4);
    float* dinv = (float*)alloc((size_t)N * 4);
    float* selfc = (float*)alloc((size_t)N * 4);
    int* bsum = (int*)alloc(256 * 4);
    float* stats = (float*)alloc(256 * 4);
    float* gsum = stats;
    float* gsumsq = stats + 128;
    unsigned short* WT1 = (unsigned short*)alloc(16384 * 2);
    unsigned short* WT2 = (unsigned short*)alloc(16384 * 2);
    unsigned short* WT3 = (unsigned short*)alloc(16384 * 2);
    unsigned short* WcT = (unsigned short*)alloc(16384 * 2);
    float* bcP = (float*)alloc(128 * 4);
    (void)ws_size; (void)n_in; (void)out_size;

    const int NBLK = (N + SCHUNK - 1) / SCHUNK;

    hipMemsetAsync(deg, 0, (size_t)N * 4, stream);
    hipMemsetAsync(stats, 0, 256 * 4, stream);

    hist_k<<<(E + 255) / 256, 256, 0, stream>>>(dstIdx, deg, E);
    dinv_k<<<(N + 255) / 256, 256, 0, stream>>>(deg, dinv, selfc, N);
    scan_partial<<<NBLK, 256, 0, stream>>>(deg, bsum, N);
    scan_bsum<<<1, 256, 0, stream>>>(bsum, row_ptr, NBLK, N);
    scan_final<<<NBLK, 256, 0, stream>>>(deg, bsum, row_ptr, cursor, N);
    scatter_k<<<(E + 255) / 256, 256, 0, stream>>>(srcIdx, dstIdx, dinv, cursor, packed, E);

    wconv_k<<<64, 256, 0, stream>>>(W1, WT1);
    wconv_k<<<64, 256, 0, stream>>>(W2, WT2);
    wconv_k<<<64, 256, 0, stream>>>(W3, WT3);

    const int gemmBlocks = (N + 127) / 128;
    const int aggBlocks = (N + 3) / 4;
    const int projBlocks = (N + 255) / 256;

    // layer 1 (A = x fp32, converted in-flight)
    gemm_k<0, 1><<<gemmBlocks, 256, 0, stream>>>(x, WT1, nullptr, bufB, N);
    agg_k<<<aggBlocks, 256, 0, stream>>>(bufB, packed, row_ptr, selfc, b1, bufA, N);
    // layer 2
    gemm_k<0, 0><<<gemmBlocks, 256, 0, stream>>>(bufA, WT2, nullptr, bufB, N);
    agg_k<<<aggBlocks, 256, 0, stream>>>(bufB, packed, row_ptr, selfc, b2, bufA, N);
    // layer 3
    gemm_k<0, 0><<<gemmBlocks, 256, 0, stream>>>(bufA, WT3, nullptr, bufB, N);
    agg_k<<<aggBlocks, 256, 0, stream>>>(bufB, packed, row_ptr, selfc, b3, bufA, N);

    // batchnorm folded into classifier
    bn_stats<<<256, 256, 0, stream>>>(bufA, gsum, gsumsq, N);
    bn_fold<<<1, 128, 0, stream>>>(gsum, gsumsq, gamma, beta, Wc, bc, WcT, bcP, 1.0f / (float)N);

    gemm_k<1, 0><<<gemmBlocks, 256, 0, stream>>>(bufA, WcT, bcP, bufB, N);
    out_proj<<<projBlocks, 256, 0, stream>>>(bufB, Wr, br, out, N);
}

// Round 3
// 500.690 us; speedup vs baseline: 2.2951x; 1.2721x over previous
//
#include <hip/hip_runtime.h>

#define DHC 128
#define BSHIFT 8
#define BSIZE 256  // dst nodes per bucket

typedef __attribute__((ext_vector_type(8))) __bf16 bf16x8;
typedef __attribute__((ext_vector_type(8))) unsigned short ushort8;
typedef __attribute__((ext_vector_type(4))) float floatx4;

__device__ inline unsigned short f2bf(float f) {
    unsigned int u = __float_as_uint(f);
    return (unsigned short)((u + 0x7FFFu + ((u >> 16) & 1u)) >> 16);
}
__device__ inline float bf2f_lo(unsigned int v) { return __uint_as_float(v << 16); }
__device__ inline float bf2f_hi(unsigned int v) { return __uint_as_float(v & 0xFFFF0000u); }

// ---------------- graph prep: bucket sort by dst>>8, then per-bucket CSR ----------------

// histogram of edges per bucket (LDS-aggregated)
__global__ __launch_bounds__(256) void bucket_hist(const int* __restrict__ dst,
                                                   int* __restrict__ bcount, int e) {
    __shared__ int h[512];
    for (int i = threadIdx.x; i < 512; i += 256) h[i] = 0;
    __syncthreads();
    int base = blockIdx.x * 4096 + threadIdx.x;
#pragma unroll
    for (int j = 0; j < 16; j++) {
        int i = base + j * 256;
        if (i < e) atomicAdd(&h[dst[i] >> BSHIFT], 1);
    }
    __syncthreads();
    for (int i = threadIdx.x; i < 512; i += 256)
        if (h[i]) atomicAdd(&bcount[i], h[i]);
}

// exclusive scan of bucket counts -> bbase; init bcur; row_ptr[n]=e; bbase[nb]=e
__global__ void bucket_scan(const int* __restrict__ bcount, int* __restrict__ bbase,
                            int* __restrict__ bcur, int* __restrict__ row_ptr,
                            int nb, int n, int e) {
    __shared__ int s[512];
    int t = threadIdx.x;
    s[t] = (t < nb) ? bcount[t] : 0;
    __syncthreads();
    for (int off = 1; off < 512; off <<= 1) {
        int add = (t >= off) ? s[t - off] : 0;
        __syncthreads();
        s[t] += add;
        __syncthreads();
    }
    if (t < nb) {
        int ex = (t == 0) ? 0 : s[t - 1];
        bbase[t] = ex;
        bcur[t] = ex;
    }
    if (t == 0) {
        bbase[nb] = e;
        row_ptr[n] = e;
    }
}

// scatter edges into bucket regions; block reserves per-bucket ranges (writes ~contiguous)
__global__ __launch_bounds__(256) void bucket_scatter(const int* __restrict__ src,
                                                      const int* __restrict__ dst,
                                                      int* __restrict__ bcur,
                                                      int2* __restrict__ ebuf, int e) {
    __shared__ int h[512];
    __shared__ int rsv[512];
    for (int i = threadIdx.x; i < 512; i += 256) h[i] = 0;
    __syncthreads();
    int base = blockIdx.x * 4096 + threadIdx.x;
    int sreg[16], dreg[16];
#pragma unroll
    for (int j = 0; j < 16; j++) {
        int i = base + j * 256;
        if (i < e) {
            sreg[j] = src[i];
            dreg[j] = dst[i];
            atomicAdd(&h[dreg[j] >> BSHIFT], 1);
        } else {
            dreg[j] = -1;
        }
    }
    __syncthreads();
    for (int i = threadIdx.x; i < 512; i += 256) {
        int c = h[i];
        rsv[i] = c ? atomicAdd(&bcur[i], c) : 0;
        h[i] = 0;
    }
    __syncthreads();
#pragma unroll
    for (int j = 0; j < 16; j++) {
        if (dreg[j] >= 0) {
            int b = dreg[j] >> BSHIFT;
            int pos = rsv[b] + atomicAdd(&h[b], 1);
            ebuf[pos] = make_int2(sreg[j], dreg[j]);
        }
    }
}

// one block per bucket: local deg, local scan -> row_ptr, dinv, selfc, csr_src (src only)
__global__ __launch_bounds__(256) void bucket_build(const int2* __restrict__ ebuf,
                                                    const int* __restrict__ bbase,
                                                    int* __restrict__ row_ptr,
                                                    int* __restrict__ csr_src,
                                                    float* __restrict__ dinv,
                                                    float* __restrict__ selfc, int n) {
    __shared__ int ldeg[256];
    __shared__ int lcur[256];
    int b = blockIdx.x;
    int d0 = b << BSHIFT;
    int t = threadIdx.x;
    int beg = bbase[b], end = bbase[b + 1];
    ldeg[t] = 0;
    __syncthreads();
    for (int i = beg + t; i < end; i += 256) atomicAdd(&ldeg[ebuf[i].y - d0], 1);
    __syncthreads();
    int deg = ldeg[t];
    lcur[t] = deg;
    __syncthreads();
    for (int off = 1; off < 256; off <<= 1) {
        int add = (t >= off) ? lcur[t - off] : 0;
        __syncthreads();
        lcur[t] += add;
        __syncthreads();
    }
    int rp = beg + lcur[t] - deg;  // exclusive
    int node = d0 + t;
    if (node < n) {
        row_ptr[node] = rp;
        float dv = rsqrtf((float)(deg + 1));
        dinv[node] = dv;
        selfc[node] = dv * dv;
    }
    __syncthreads();
    lcur[t] = rp;
    __syncthreads();
    for (int i = beg + t; i < end; i += 256) {
        int2 p = ebuf[i];
        int pos = atomicAdd(&lcur[p.y - d0], 1);
        csr_src[pos] = p.x;
    }
}

// ---------------- weight convert: W[128k][128n] fp32 -> WT[n][k] bf16 ----------------
__global__ void wconv_k(const float* __restrict__ W, unsigned short* __restrict__ WT) {
    int i = blockIdx.x * 256 + threadIdx.x;  // 16384
    int nn = i >> 7, k = i & 127;
    WT[i] = f2bf(W[k * 128 + nn]);
}

// ---------------- MFMA bf16 GEMM: out = A[N,128] @ W ----------------
// MODE 0: bf16 store. MODE 2: fused classifier epilogue: relu(acc+bias) @ Wr + br -> fp32 outF[N,2].
// AF32: A is fp32 (convert in-flight), else bf16.
template <int MODE, int AF32>
__global__ __launch_bounds__(256) void gemm_k(const void* __restrict__ Avoid,
                                              const unsigned short* __restrict__ WT,
                                              const float* __restrict__ bias,
                                              unsigned short* __restrict__ outB,
                                              float* __restrict__ outF,
                                              const float* __restrict__ Wr,
                                              const float* __restrict__ br, int n) {
    __shared__ unsigned short Ws[32 * 512];
    {
        for (int c = threadIdx.x; c < 2048; c += 256) {
            int f = c >> 6;
            int l = c & 63;
            int ks = f >> 3, ct = f & 7;
            int nn = ct * 16 + (l & 15);
            int kb = ks * 32 + (l >> 4) * 8;
            *(uint4*)(&Ws[c * 8]) = *(const uint4*)(&WT[nn * 128 + kb]);
        }
    }
    __syncthreads();
    const int wave = threadIdx.x >> 6;
    const int lane = threadIdx.x & 63;
    const int rowbase = blockIdx.x * 128 + wave * 32;
    const int m = lane & 15;
    const int kq = lane >> 4;  // 0..3

    floatx4 acc[2][8];
#pragma unroll
    for (int rt = 0; rt < 2; rt++)
#pragma unroll
        for (int ct = 0; ct < 8; ct++) acc[rt][ct] = (floatx4){0.f, 0.f, 0.f, 0.f};

    const int r0 = min(rowbase + m, n - 1);
    const int r1 = min(rowbase + 16 + m, n - 1);

#pragma unroll
    for (int ks = 0; ks < 4; ks++) {
        const int kb = ks * 32 + kq * 8;
        bf16x8 a0, a1;
        if (AF32) {
            const float* Af = (const float*)Avoid;
            float4 f00 = *(const float4*)(Af + (size_t)r0 * 128 + kb);
            float4 f01 = *(const float4*)(Af + (size_t)r0 * 128 + kb + 4);
            float4 f10 = *(const float4*)(Af + (size_t)r1 * 128 + kb);
            float4 f11 = *(const float4*)(Af + (size_t)r1 * 128 + kb + 4);
            ushort8 u0, u1;
            u0[0] = f2bf(f00.x); u0[1] = f2bf(f00.y); u0[2] = f2bf(f00.z); u0[3] = f2bf(f00.w);
            u0[4] = f2bf(f01.x); u0[5] = f2bf(f01.y); u0[6] = f2bf(f01.z); u0[7] = f2bf(f01.w);
            u1[0] = f2bf(f10.x); u1[1] = f2bf(f10.y); u1[2] = f2bf(f10.z); u1[3] = f2bf(f10.w);
            u1[4] = f2bf(f11.x); u1[5] = f2bf(f11.y); u1[6] = f2bf(f11.z); u1[7] = f2bf(f11.w);
            a0 = __builtin_bit_cast(bf16x8, u0);
            a1 = __builtin_bit_cast(bf16x8, u1);
        } else {
            const unsigned short* Ab = (const unsigned short*)Avoid;
            a0 = __builtin_bit_cast(bf16x8, *(const ushort8*)(Ab + (size_t)r0 * 128 + kb));
            a1 = __builtin_bit_cast(bf16x8, *(const ushort8*)(Ab + (size_t)r1 * 128 + kb));
        }
#pragma unroll
        for (int ct = 0; ct < 8; ct++) {
            bf16x8 bfr = __builtin_bit_cast(bf16x8,
                *(const ushort8*)(&Ws[(ks * 8 + ct) * 512 + lane * 8]));
            acc[0][ct] = __builtin_amdgcn_mfma_f32_16x16x32_bf16(a0, bfr, acc[0][ct], 0, 0, 0);
            acc[1][ct] = __builtin_amdgcn_mfma_f32_16x16x32_bf16(a1, bfr, acc[1][ct], 0, 0, 0);
        }
    }

    if (MODE == 0) {
#pragma unroll
        for (int rt = 0; rt < 2; rt++) {
#pragma unroll
            for (int ct = 0; ct < 8; ct++) {
                int col = ct * 16 + m;
#pragma unroll
                for (int i = 0; i < 4; i++) {
                    int r = rowbase + rt * 16 + kq * 4 + i;
                    if (r < n) outB[(size_t)r * 128 + col] = f2bf(acc[rt][ct][i]);
                }
            }
        }
    } else {
        float bcv[8], wr0[8], wr1[8];
#pragma unroll
        for (int ct = 0; ct < 8; ct++) {
            int col = ct * 16 + m;
            bcv[ct] = bias[col];
            float2 wv = ((const float2*)Wr)[col];
            wr0[ct] = wv.x;
            wr1[ct] = wv.y;
        }
        float br0 = br[0], br1 = br[1];
#pragma unroll
        for (int rt = 0; rt < 2; rt++) {
#pragma unroll
            for (int i = 0; i < 4; i++) {
                float p0 = 0.f, p1 = 0.f;
#pragma unroll
                for (int ct = 0; ct < 8; ct++) {
                    float v = fmaxf(acc[rt][ct][i] + bcv[ct], 0.f);
                    p0 = fmaf(v, wr0[ct], p0);
                    p1 = fmaf(v, wr1[ct], p1);
                }
#pragma unroll
                for (int mk = 1; mk < 16; mk <<= 1) {
                    p0 += __shfl_xor(p0, mk);
                    p1 += __shfl_xor(p1, mk);
                }
                int r = rowbase + rt * 16 + kq * 4 + i;
                if (m == 0 && r < n) ((float2*)outF)[r] = make_float2(p0 + br0, p1 + br1);
            }
        }
    }
}

// ---------------- CSR gather aggregation: 16 lanes x 16B per edge row, 4 edges/wave ----------------
__global__ __launch_bounds__(256) void agg_k(const unsigned short* __restrict__ hW,
                                             const int* __restrict__ csr,
                                             const int* __restrict__ row_ptr,
                                             const float* __restrict__ dinv,
                                             const float* __restrict__ selfc,
                                             const float* __restrict__ bias,
                                             unsigned short* __restrict__ out, int n) {
    int node = blockIdx.x * 4 + (threadIdx.x >> 6);
    int lane = threadIdx.x & 63;
    if (node >= n) return;
    int g = lane >> 4, t = lane & 15;
    int beg = row_ptr[node], end = row_ptr[node + 1];
    float dd = dinv[node];
    const uint4* h4 = (const uint4*)hW;
    float a[8];
#pragma unroll
    for (int i = 0; i < 8; i++) a[i] = 0.f;

    auto edge = [&](int e) {
        int s = csr[e];
        float c = dinv[s] * dd;
        uint4 v = h4[(size_t)s * 16 + t];
        a[0] = fmaf(c, bf2f_lo(v.x), a[0]);
        a[1] = fmaf(c, bf2f_hi(v.x), a[1]);
        a[2] = fmaf(c, bf2f_lo(v.y), a[2]);
        a[3] = fmaf(c, bf2f_hi(v.y), a[3]);
        a[4] = fmaf(c, bf2f_lo(v.z), a[4]);
        a[5] = fmaf(c, bf2f_hi(v.z), a[5]);
        a[6] = fmaf(c, bf2f_lo(v.w), a[6]);
        a[7] = fmaf(c, bf2f_hi(v.w), a[7]);
    };
    int e = beg + g;
    for (; e + 4 < end; e += 8) {
        edge(e);
        edge(e + 4);
    }
    if (e < end) edge(e);

    if (g == 0) {  // self-loop contribution in group 0
        float sc = selfc[node];
        uint4 v = h4[(size_t)node * 16 + t];
        a[0] = fmaf(sc, bf2f_lo(v.x), a[0]);
        a[1] = fmaf(sc, bf2f_hi(v.x), a[1]);
        a[2] = fmaf(sc, bf2f_lo(v.y), a[2]);
        a[3] = fmaf(sc, bf2f_hi(v.y), a[3]);
        a[4] = fmaf(sc, bf2f_lo(v.z), a[4]);
        a[5] = fmaf(sc, bf2f_hi(v.z), a[5]);
        a[6] = fmaf(sc, bf2f_lo(v.w), a[6]);
        a[7] = fmaf(sc, bf2f_hi(v.w), a[7]);
    }
#pragma unroll
    for (int i = 0; i < 8; i++) {
        a[i] += __shfl_xor(a[i], 16);
        a[i] += __shfl_xor(a[i], 32);
    }
    if (g == 0) {
        float4 b0 = ((const float4*)bias)[t * 2];
        float4 b1 = ((const float4*)bias)[t * 2 + 1];
        uint4 o;
        o.x = (unsigned int)f2bf(fmaxf(a[0] + b0.x, 0.f)) |
              ((unsigned int)f2bf(fmaxf(a[1] + b0.y, 0.f)) << 16);
        o.y = (unsigned int)f2bf(fmaxf(a[2] + b0.z, 0.f)) |
              ((unsigned int)f2bf(fmaxf(a[3] + b0.w, 0.f)) << 16);
        o.z = (unsigned int)f2bf(fmaxf(a[4] + b1.x, 0.f)) |
              ((unsigned int)f2bf(fmaxf(a[5] + b1.y, 0.f)) << 16);
        o.w = (unsigned int)f2bf(fmaxf(a[6] + b1.z, 0.f)) |
              ((unsigned int)f2bf(fmaxf(a[7] + b1.w, 0.f)) << 16);
        ((uint4*)out)[(size_t)node * 16 + t] = o;
    }
}

// ---------------- BN stats (per-channel sum / sumsq) over bf16 h ----------------
__global__ __launch_bounds__(256) void bn_stats(const unsigned short* __restrict__ h,
                                                float* __restrict__ gsum,
                                                float* __restrict__ gsumsq, int n) {
    __shared__ float red[4][256];
    int l = threadIdx.x & 63;
    int rs = threadIdx.x >> 6;
    float s0 = 0.f, s1 = 0.f, q0 = 0.f, q1 = 0.f;
    for (int r = blockIdx.x * 4 + rs; r < n; r += gridDim.x * 4) {
        unsigned int v = *(const unsigned int*)(h + (size_t)r * 128 + l * 2);
        float a = bf2f_lo(v), b = bf2f_hi(v);
        s0 += a;
        s1 += b;
        q0 = fmaf(a, a, q0);
        q1 = fmaf(b, b, q1);
    }
    red[0][threadIdx.x] = s0;
    red[1][threadIdx.x] = s1;
    red[2][threadIdx.x] = q0;
    red[3][threadIdx.x] = q1;
    __syncthreads();
    if (threadIdx.x < 64) {
        float S0 = 0.f, S1 = 0.f, Q0 = 0.f, Q1 = 0.f;
#pragma unroll
        for (int j = 0; j < 4; j++) {
            S0 += red[0][j * 64 + l];
            S1 += red[1][j * 64 + l];
            Q0 += red[2][j * 64 + l];
            Q1 += red[3][j * 64 + l];
        }
        atomicAdd(&gsum[2 * l + 0], S0);
        atomicAdd(&gsum[2 * l + 1], S1);
        atomicAdd(&gsumsq[2 * l + 0], Q0);
        atomicAdd(&gsumsq[2 * l + 1], Q1);
    }
}

// ---------------- fold BN into Wc ----------------
__global__ void bn_fold(const float* __restrict__ gsum, const float* __restrict__ gsumsq,
                        const float* __restrict__ gamma, const float* __restrict__ beta,
                        const float* __restrict__ Wc, const float* __restrict__ bc,
                        unsigned short* __restrict__ WcT, float* __restrict__ bcP, float invN) {
    __shared__ float scaleS[128], shiftS[128];
    int j = threadIdx.x;
    float mu = gsum[j] * invN;
    float var = gsumsq[j] * invN - mu * mu;
    float sc = gamma[j] * rsqrtf(var + 1e-5f);
    scaleS[j] = sc;
    shiftS[j] = beta[j] - mu * sc;
    __syncthreads();
    float accB = bc[j];
    for (int k = 0; k < 128; k++) {
        float w = Wc[k * 128 + j];
        WcT[j * 128 + k] = f2bf(scaleS[k] * w);
        accB = fmaf(shiftS[k], w, accB);
    }
    bcP[j] = accB;
}

// ---------------- host ----------------

extern "C" void kernel_launch(void* const* d_in, const int* in_sizes, int n_in,
                              void* d_out, int out_size, void* d_ws, size_t ws_size,
                              hipStream_t stream) {
    const float* x = (const float*)d_in[0];
    const int* ei = (const int*)d_in[1];
    const float* W1 = (const float*)d_in[2];
    const float* b1 = (const float*)d_in[3];
    const float* W2 = (const float*)d_in[4];
    const float* b2 = (const float*)d_in[5];
    const float* W3 = (const float*)d_in[6];
    const float* b3 = (const float*)d_in[7];
    const float* gamma = (const float*)d_in[8];
    const float* beta = (const float*)d_in[9];
    const float* Wc = (const float*)d_in[10];
    const float* bc = (const float*)d_in[11];
    const float* Wr = (const float*)d_in[12];
    const float* br = (const float*)d_in[13];
    float* out = (float*)d_out;

    const int N = in_sizes[0] / DHC;
    const int E = in_sizes[1] / 2;
    const int* srcIdx = ei;
    const int* dstIdx = ei + E;
    const int NB = (N + BSIZE - 1) >> BSHIFT;

    char* w = (char*)d_ws;
    size_t off = 0;
    auto alloc = [&](size_t bytes) -> void* {
        void* p = w + off;
        off += (bytes + 255) & ~(size_t)255;
        return p;
    };
    unsigned short* bufA = (unsigned short*)alloc((size_t)N * DHC * 2);
    unsigned short* bufB = (unsigned short*)alloc((size_t)N * DHC * 2);
    int2* ebuf = (int2*)alloc((size_t)E * 8);
    int* csr_src = (int*)alloc((size_t)E * 4);
    int* row_ptr = (int*)alloc((size_t)(N + 1) * 4);
    float* dinv = (float*)alloc((size_t)N * 4);
    float* selfc = (float*)alloc((size_t)N * 4);
    int* bcount = (int*)alloc(512 * 4);
    int* bbase = (int*)alloc(512 * 4);
    int* bcur = (int*)alloc(512 * 4);
    float* stats = (float*)alloc(256 * 4);
    float* gsum = stats;
    float* gsumsq = stats + 128;
    unsigned short* WT1 = (unsigned short*)alloc(16384 * 2);
    unsigned short* WT2 = (unsigned short*)alloc(16384 * 2);
    unsigned short* WT3 = (unsigned short*)alloc(16384 * 2);
    unsigned short* WcT = (unsigned short*)alloc(16384 * 2);
    float* bcP = (float*)alloc(128 * 4);
    (void)ws_size; (void)n_in; (void)out_size;

    hipMemsetAsync(bcount, 0, 512 * 4, stream);
    hipMemsetAsync(stats, 0, 256 * 4, stream);

    const int EB = (E + 4095) / 4096;
    bucket_hist<<<EB, 256, 0, stream>>>(dstIdx, bcount, E);
    bucket_scan<<<1, 512, 0, stream>>>(bcount, bbase, bcur, row_ptr, NB, N, E);
    bucket_scatter<<<EB, 256, 0, stream>>>(srcIdx, dstIdx, bcur, ebuf, E);
    bucket_build<<<NB, 256, 0, stream>>>(ebuf, bbase, row_ptr, csr_src, dinv, selfc, N);

    wconv_k<<<64, 256, 0, stream>>>(W1, WT1);
    wconv_k<<<64, 256, 0, stream>>>(W2, WT2);
    wconv_k<<<64, 256, 0, stream>>>(W3, WT3);

    const int gemmBlocks = (N + 127) / 128;
    const int aggBlocks = (N + 3) / 4;

    // layer 1 (A = x fp32, converted in-flight)
    gemm_k<0, 1><<<gemmBlocks, 256, 0, stream>>>(x, WT1, nullptr, bufB, nullptr, nullptr, nullptr, N);
    agg_k<<<aggBlocks, 256, 0, stream>>>(bufB, csr_src, row_ptr, dinv, selfc, b1, bufA, N);
    // layer 2
    gemm_k<0, 0><<<gemmBlocks, 256, 0, stream>>>(bufA, WT2, nullptr, bufB, nullptr, nullptr, nullptr, N);
    agg_k<<<aggBlocks, 256, 0, stream>>>(bufB, csr_src, row_ptr, dinv, selfc, b2, bufA, N);
    // layer 3
    gemm_k<0, 0><<<gemmBlocks, 256, 0, stream>>>(bufA, WT3, nullptr, bufB, nullptr, nullptr, nullptr, N);
    agg_k<<<aggBlocks, 256, 0, stream>>>(bufB, csr_src, row_ptr, dinv, selfc, b3, bufA, N);

    // batchnorm folded into classifier; classifier GEMM fused with output projection
    bn_stats<<<256, 256, 0, stream>>>(bufA, gsum, gsumsq, N);
    bn_fold<<<1, 128, 0, stream>>>(gsum, gsumsq, gamma, beta, Wc, bc, WcT, bcP, 1.0f / (float)N);
    gemm_k<2, 0><<<gemmBlocks, 256, 0, stream>>>(bufA, WcT, bcP, nullptr, out, Wr, br, N);
}